// Round 13
// baseline (2720.358 us; speedup 1.0000x reference)
//
#include <hip/hip_runtime.h>
#include <math.h>

#define B_      4
#define F_BINS  128
#define T_FULL  16384
#define KF      33
#define KT      129

// conv tile geometry: f-tile 32 planes x TT 64 t per block (4 waves x 16 t)
#define TT      64
#define ROWS    196                // max staged row read = 194
#define PITCH   72                 // ushort pitch for 64 f cols (16B-aligned rows)
#define DTP     136                // padded dt rows (129 + prefetch overrun pad)
#define D2R     48                 // row: cols 0..39 = F frags u=0..4, 40..47 = G4

typedef __attribute__((ext_vector_type(8))) short short8;
typedef __attribute__((ext_vector_type(4))) float f32x4;
typedef uint uint4a16 __attribute__((ext_vector_type(4), aligned(16)));

union ABFrag { uint4a16 u; short8 v; };

__device__ __forceinline__ ushort f2bf(float v) {
  unsigned u = __float_as_uint(v);
  unsigned r = (u + 0x7FFFu + ((u >> 16) & 1u)) >> 16;
  return (ushort)r;
}

__device__ __forceinline__ short8 load_a16(const ushort* p) {
  ABFrag f; f.u = *(const uint4a16*)p; return f.v;
}

__device__ __forceinline__ short8 mkG(short8 a, short8 b) {
  return __builtin_shufflevector(a, b, 4, 5, 6, 7, 8, 9, 10, 11);
}

// ---------------------------------------------------------------------------
// prep_w: wq[oct 4][gam 4][ch 16][dt 136][d2 48]
//   cols 0..39  (F part):  df = d2 - 4 - gam          (R7's F layout)
//   cols 40..47 (G4 part): df = d2 - 8 - gam          (= F-space d2 36..43,
//                           i.e. R7's G[4] = mkG(F[4],F[5]), memory-materialized)
// zero outside df in [0,33), dt in [0,129).
// ---------------------------------------------------------------------------
__global__ __launch_bounds__(256) void prep_w(
    const float* __restrict__ wr, const float* __restrict__ wi,
    ushort* __restrict__ wq) {
  int idx = blockIdx.x * 256 + threadIdx.x;      // 4*4*16*136*48 = 1671168
  int d2  = idx % D2R;
  int dt  = (idx / D2R) % DTP;
  int ch  = (idx / (D2R * DTP)) % 16;
  int gam = (idx / (D2R * DTP * 16)) % 4;
  int oct = idx / (D2R * DTP * 16 * 4);
  int df  = d2 - 4 - gam - (d2 >= 40 ? 4 : 0);
  float v = 0.f;
  if (df >= 0 && df < KF && dt < KT) {
    const float* src = (ch < 8) ? wr : wi;
    v = src[(((size_t)oct * 8 + (ch & 7)) * KF + df) * KT + dt];
  }
  wq[idx] = f2bf(v);
}

// ---------------------------------------------------------------------------
// prep_x: bf16 transposed pyramid  xTj[b][T_j][128f]  for j=0..3
// ---------------------------------------------------------------------------
__global__ __launch_bounds__(256) void prep_x(
    const float* __restrict__ x,
    ushort* __restrict__ xT0, ushort* __restrict__ xT1,
    ushort* __restrict__ xT2, ushort* __restrict__ xT3) {
  __shared__ float lt[128 * 65];
  const int b  = blockIdx.y;
  const int t0 = blockIdx.x * 64;
  const int tid = threadIdx.x;
  const int wv = tid >> 6, lane = tid & 63;
#pragma unroll
  for (int rep = 0; rep < 32; ++rep) {
    int f = rep * 4 + wv;
    lt[f * 65 + lane] = x[((size_t)b * 128 + f) * T_FULL + t0 + lane];
  }
  __syncthreads();
  ushort* dst[4] = {xT0, xT1, xT2, xT3};
  const int Ts[4] = {16384, 8192, 4096, 2048};
  for (int lvl = 0; lvl < 4; ++lvl) {
    int nt = 64 >> lvl, w = 1 << lvl;
    float inv = 1.f / (float)w;
    int tasks = nt * 16;
    for (int i = tid; i < tasks; i += 256) {
      int tl = i >> 4, fc = i & 15;
      __align__(16) ushort vs[8];
#pragma unroll
      for (int e = 0; e < 8; ++e) {
        float a = 0.f;
        for (int m = 0; m < w; ++m) a += lt[(fc * 8 + e) * 65 + tl * w + m];
        vs[e] = f2bf(a * inv);
      }
      ushort* pdst = dst[lvl] + ((size_t)b * Ts[lvl] + (t0 >> lvl) + tl) * 128 + fc * 8;
      *(uint4*)pdst = *(const uint4*)vs;
    }
  }
}

// ---------------------------------------------------------------------------
// conv_mfma: ALL octaves fused, 7680 equal-work blocks:
//   [0,4096) oct0, [4096,6144) oct1, [6144,7168) oct2, [7168,7680) oct3.
// Block = 4 waves; tile = 32 f_out x 64 t (16 t per wave, fr=1).
// MFMA 16x16x32_bf16: M=ch16, N=pos16, K=(4 dt x 8 d2).
// TWO gamma planes fused per pass (gp=0: gammas 0,1; gp=1: gammas 2,3):
// the B fragment bv (gamma-independent) feeds 16 chains instead of 8 ->
// LDS reads per MFMA halved (8 reads / 80 MFMAs per c) -> matrix-bound.
// Chains per gamma k=0..7, plane fo = f0 + gamma + 4k:
//   odd k: A = F[s-(k-1)/2]; even k: A = G[s-k/2]; active s in [SLO, SLO+4].
// F streams from wq cols 0..39 (R7 schedule: F[u] reloaded in-place at s=u+3);
// G[0..3] register-built (R7 slots: s=6,7 and next-c s=0,1); G[4] streamed
// from wq cols 40..47 at s=7 (mostly-zero tail fragment).
// Epilogue deduped: lo lanes finish r=0,1; hi lanes finish r=2,3.
// ---------------------------------------------------------------------------
__global__ __launch_bounds__(256, 3) void conv_mfma(
    const ushort* __restrict__ xT0, const ushort* __restrict__ xT1,
    const ushort* __restrict__ xT2, const ushort* __restrict__ xT3,
    const ushort* __restrict__ wq, float* __restrict__ out) {
  __shared__ ushort xt[ROWS * PITCH];
  const int tid = threadIdx.x;
  const int bx = blockIdx.x;

  int oct, local, nxs;
  if (bx < 4096)      { oct = 0; local = bx;        nxs = 8; }
  else if (bx < 6144) { oct = 1; local = bx - 4096; nxs = 7; }
  else if (bx < 7168) { oct = 2; local = bx - 6144; nxs = 6; }
  else                { oct = 3; local = bx - 7168; nxs = 5; }
  const ushort* xT = (oct == 0) ? xT0 : (oct == 1) ? xT1 : (oct == 2) ? xT2 : xT3;
  const int Tj  = T_FULL >> oct;
  const int lw  = 4 - oct;                    // pool window = 1<<lw
  const int tx   = local & ((1 << nxs) - 1);
  const int rest = local >> nxs;
  const int t0 = tx * TT;
  const int f0 = (rest & 3) * 32;
  const int b  = rest >> 2;

  // ---- stage transposed x tile: rows 0..195 (t = t0-64+row), cols f0-16+[0,64) ----
  for (int i = tid; i < ROWS * 8; i += 256) {
    int row = i >> 3, fc = i & 7;
    int t = t0 - 64 + row;
    int f = f0 - 16 + fc * 8;
    uint4 v = make_uint4(0u, 0u, 0u, 0u);
    if (t >= 0 && t < Tj && f >= 0 && f < 128)
      v = *(const uint4*)(xT + ((size_t)b * Tj + t) * 128 + f);
    *(uint4*)&xt[row * PITCH + fc * 8] = v;
  }
  __syncthreads();

  const int wave = tid >> 6, lane = tid & 63;
  const int p = lane & 15;                 // A-row = channel sel, B-col = position
  const int g = lane >> 4;                 // k-group (dt sub-index)
  const int hi = (lane >= 32);
  const float invw = 1.0f / (float)(1 << lw);

  for (int gp = 0; gp < 2; ++gp) {
    const int gA = 2 * gp, gB = 2 * gp + 1;
    const ushort* wpA = wq + ((((size_t)oct * 4 + gA) * 16 + p) * DTP + g) * D2R;
    const ushort* wpB = wq + ((((size_t)oct * 4 + gB) * 16 + p) * DTP + g) * D2R;
    int rb = (p + g) * PITCH + wave * (16 * PITCH);

    f32x4 aA[8], aB[8];
#pragma unroll
    for (int k = 0; k < 8; ++k) {
      f32x4 z = {0.f, 0.f, 0.f, 0.f};
      aA[k] = z; aB[k] = z;
    }

    short8 FA[5], GA[5], FB[5], GB[5];
#pragma unroll
    for (int u = 0; u < 5; ++u) {
      FA[u] = load_a16(wpA + 8 * u);
      FB[u] = load_a16(wpB + 8 * u);
    }
    GA[4] = load_a16(wpA + 40);
    GB[4] = load_a16(wpB + 40);
#pragma unroll
    for (int u = 0; u < 4; ++u) {
      GA[u] = mkG(FA[u], FA[u + 1]);
      GB[u] = mkG(FB[u], FB[u + 1]);
    }
    wpA += 4 * D2R;                 // in-body loads fetch c+1
    wpB += 4 * D2R;

#pragma unroll 1
    for (int c = 0; c < 33; ++c) {
      __builtin_amdgcn_s_setprio(1);
      const int SLO[8] = {0, 0, 1, 1, 2, 2, 3, 3};
#pragma unroll
      for (int s = 0; s < 8; ++s) {
        short8 bv = *(const short8*)&xt[rb + s * 8];
#pragma unroll
        for (int k = 0; k < 8; ++k) {
          if (s >= SLO[k] && s <= SLO[k] + 4) {
            const int idx = s - SLO[k];
            aA[k] = __builtin_amdgcn_mfma_f32_16x16x32_bf16(
                (k & 1) ? FA[idx] : GA[idx], bv, aA[k], 0, 0, 0);
            aB[k] = __builtin_amdgcn_mfma_f32_16x16x32_bf16(
                (k & 1) ? FB[idx] : GB[idx], bv, aB[k], 0, 0, 0);
          }
        }
        // R7 rebuild/prefetch schedule, applied to both gammas:
        if (s == 0) { GA[2] = mkG(FA[2], FA[3]); GB[2] = mkG(FB[2], FB[3]); }
        if (s == 1) { GA[3] = mkG(FA[3], FA[4]); GB[3] = mkG(FB[3], FB[4]); }
        if (s >= 3) {
          FA[s - 3] = load_a16(wpA + 8 * (s - 3));
          FB[s - 3] = load_a16(wpB + 8 * (s - 3));
        }
        if (s == 6) { GA[0] = mkG(FA[0], FA[1]); GB[0] = mkG(FB[0], FB[1]); }
        if (s == 7) {
          GA[1] = mkG(FA[1], FA[2]); GB[1] = mkG(FB[1], FB[2]);
          GA[4] = load_a16(wpA + 40); GB[4] = load_a16(wpB + 40);
        }
      }
      __builtin_amdgcn_s_setprio(0);
      wpA += 4 * D2R;              // dt += 4
      wpB += 4 * D2R;
      rb  += 4 * PITCH;
    }

    // ---- epilogue: modulus + avg-pool, deduped across lane halves ----
    auto epi = [&](f32x4 (&acc)[8], int gamma) {
#pragma unroll
      for (int k = 0; k < 8; ++k) {
        const int fo = f0 + gamma + 4 * k;
        const int tbase = t0 + 16 * wave;
        float sq[4];
#pragma unroll
        for (int r = 0; r < 4; ++r) {
          float a = acc[k][r];
          float o = __shfl_xor(a, 32);
          sq[r] = a * a + o * o;
        }
        float m0 = sqrtf(hi ? sq[2] : sq[0]);
        float m1 = sqrtf(hi ? sq[3] : sq[1]);
        if (lw == 4) { m0 += __shfl_xor(m0, 8); m1 += __shfl_xor(m1, 8); }
        if (lw >= 3) { m0 += __shfl_xor(m0, 4); m1 += __shfl_xor(m1, 4); }
        if (lw >= 2) { m0 += __shfl_xor(m0, 2); m1 += __shfl_xor(m1, 2); }
        m0 += __shfl_xor(m0, 1);  m1 += __shfl_xor(m1, 1);
        if ((p & ((1 << lw) - 1)) == 0) {
          const int ch0 = 4 * (g & 1) + (hi ? 2 : 0);
          const int tcol = (tbase + p) >> lw;
          size_t o0 = (((size_t)b * 32 + oct * 8 + ch0) * 128 + fo) * 1024 + tcol;
          out[o0] = m0 * invw;
          out[o0 + (size_t)128 * 1024] = m1 * invw;   // ch0+1
        }
      }
    };
    epi(aA, gA);
    epi(aB, gB);
  }
}

// ---------------------------------------------------------------------------
extern "C" void kernel_launch(void* const* d_in, const int* in_sizes, int n_in,
                              void* d_out, int out_size, void* d_ws, size_t ws_size,
                              hipStream_t stream) {
  const float* x  = (const float*)d_in[0];
  const float* wr = (const float*)d_in[1];
  const float* wi = (const float*)d_in[2];
  float* out = (float*)d_out;

  ushort* xT0 = (ushort*)d_ws;                       // 4*16384*128
  ushort* xT1 = xT0 + (size_t)4 * 16384 * 128;       // 4*8192*128
  ushort* xT2 = xT1 + (size_t)4 * 8192 * 128;        // 4*4096*128
  ushort* xT3 = xT2 + (size_t)4 * 4096 * 128;        // 4*2048*128
  ushort* wq  = xT3 + (size_t)4 * 2048 * 128;        // 1671168

  prep_w<<<1671168 / 256, 256, 0, stream>>>(wr, wi, wq);
  prep_x<<<dim3(T_FULL / 64, B_), 256, 0, stream>>>(x, xT0, xT1, xT2, xT3);

  conv_mfma<<<7680, 256, 0, stream>>>(xT0, xT1, xT2, xT3, wq, out);
}

// Round 14
// 1966.209 us; speedup vs baseline: 1.3836x; 1.3836x over previous
//
#include <hip/hip_runtime.h>
#include <math.h>

#define B_      4
#define F_BINS  128
#define T_FULL  16384
#define KF      33
#define KT      129

// conv tile geometry: 32 f-planes x 128 t per block, 4 waves (32 t each)
#define TT      128
#define ROWS    260                // max row 256 + pad
#define PITCH   72                 // ushort pitch for 64 f cols (144B rows, 16B-aligned)
#define DTP     132                // padded dt rows in wq
#define D2      40                 // d2 (df) window: 5 fragments of 8

typedef __attribute__((ext_vector_type(8)))  short short8;
typedef __attribute__((ext_vector_type(16))) float f32x16;
typedef uint uint4a16 __attribute__((ext_vector_type(4), aligned(16)));

union ABFrag { uint4a16 u; short8 v; };

__device__ __forceinline__ ushort f2bf(float v) {
  unsigned u = __float_as_uint(v);
  unsigned r = (u + 0x7FFFu + ((u >> 16) & 1u)) >> 16;
  return (ushort)r;
}

__device__ __forceinline__ short8 load_a16(const ushort* p) {
  ABFrag f; f.u = *(const uint4a16*)p; return f.v;
}

// ---------------------------------------------------------------------------
// prep_w: wq[oct 4][rho 4][ps 2][ch 16][dt 132][d2 40]
//         = wav[ch][df = d2 - rho - 4*ps][dt]   (zero outside df/dt range)
// All output planes fo = f0 + rho + 4*ps + 8*k come from pure 8-aligned
// fragment shifts of this layout (no register concats needed).
// ---------------------------------------------------------------------------
__global__ __launch_bounds__(256) void prep_w(
    const float* __restrict__ wr, const float* __restrict__ wi,
    ushort* __restrict__ wq) {
  int idx = blockIdx.x * 256 + threadIdx.x;      // 4*4*2*16*132*40 = 2703360
  int d2  = idx % D2;
  int dt  = (idx / D2) % DTP;
  int ch  = (idx / (D2 * DTP)) % 16;
  int ps  = (idx / (D2 * DTP * 16)) % 2;
  int rho = (idx / (D2 * DTP * 16 * 2)) % 4;
  int oct = idx / (D2 * DTP * 16 * 2 * 4);
  int df  = d2 - rho - 4 * ps;
  float v = 0.f;
  if (df >= 0 && df < KF && dt < KT) {
    const float* src = (ch < 8) ? wr : wi;
    v = src[(((size_t)oct * 8 + (ch & 7)) * KF + df) * KT + dt];
  }
  wq[idx] = f2bf(v);
}

// ---------------------------------------------------------------------------
// prep_x: bf16 transposed pyramid  xTj[b][T_j][128f]  for j=0..3
// ---------------------------------------------------------------------------
__global__ __launch_bounds__(256) void prep_x(
    const float* __restrict__ x,
    ushort* __restrict__ xT0, ushort* __restrict__ xT1,
    ushort* __restrict__ xT2, ushort* __restrict__ xT3) {
  __shared__ float lt[128 * 65];
  const int b  = blockIdx.y;
  const int t0 = blockIdx.x * 64;
  const int tid = threadIdx.x;
  const int wv = tid >> 6, lane = tid & 63;
#pragma unroll
  for (int rep = 0; rep < 32; ++rep) {
    int f = rep * 4 + wv;
    lt[f * 65 + lane] = x[((size_t)b * 128 + f) * T_FULL + t0 + lane];
  }
  __syncthreads();
  ushort* dst[4] = {xT0, xT1, xT2, xT3};
  const int Ts[4] = {16384, 8192, 4096, 2048};
  for (int lvl = 0; lvl < 4; ++lvl) {
    int nt = 64 >> lvl, w = 1 << lvl;
    float inv = 1.f / (float)w;
    int tasks = nt * 16;
    for (int i = tid; i < tasks; i += 256) {
      int tl = i >> 4, fc = i & 15;
      __align__(16) ushort vs[8];
#pragma unroll
      for (int e = 0; e < 8; ++e) {
        float a = 0.f;
        for (int m = 0; m < w; ++m) a += lt[(fc * 8 + e) * 65 + tl * w + m];
        vs[e] = f2bf(a * inv);
      }
      ushort* pdst = dst[lvl] + ((size_t)b * Ts[lvl] + (t0 >> lvl) + tl) * 128 + fc * 8;
      *(uint4*)pdst = *(const uint4*)vs;
    }
  }
}

// ---------------------------------------------------------------------------
// conv_mfma: all octaves fused, 3840 equal-work blocks.
// MFMA 32x32x16_bf16: M=32=(ps2 x ch16), N=32 positions, K=(2dt x 8d2).
// Per rho pass: 4 chains k=0..3, plane fo = f0 + rho + 4*ps + 8*k;
// chain k active at s in [k, k+4] with A = F[s-k].
// FLATTENED SCHEDULE: interleave c's ascending half (s=0..3) with (c-1)'s
// descending half (s=4..7) -> constant 5 MFMAs per slot (was 1,2,3,4,4,3,2,1
// diamond), so same-accumulator issue spacing >= ~4 MFMAs everywhere.
// Per-acc accumulation order stays (c,s)-lexicographic == R9 bit-identical.
// A-stream triple-buffered (F0/F1/F2): loads issued 2 halves before use.
// ---------------------------------------------------------------------------
__global__ __launch_bounds__(256, 3) void conv_mfma(
    const ushort* __restrict__ xT0, const ushort* __restrict__ xT1,
    const ushort* __restrict__ xT2, const ushort* __restrict__ xT3,
    const ushort* __restrict__ wq, float* __restrict__ out) {
  __shared__ ushort xt[ROWS * PITCH];
  const int tid = threadIdx.x;
  const int bx = blockIdx.x;

  int oct, local;
  if (bx < 2048)      { oct = 0; local = bx; }
  else if (bx < 3072) { oct = 1; local = bx - 2048; }
  else if (bx < 3584) { oct = 2; local = bx - 3072; }
  else                { oct = 3; local = bx - 3584; }
  const ushort* xT = (oct == 0) ? xT0 : (oct == 1) ? xT1 : (oct == 2) ? xT2 : xT3;
  const int Tj  = T_FULL >> oct;
  const int lw  = 4 - oct;                    // pool window = 1<<lw
  const int nxs = 7 - oct;
  const int tx   = local & ((1 << nxs) - 1);
  const int rest = local >> nxs;
  const int t0 = tx * TT;
  const int f0 = (rest & 3) * 32;
  const int b  = rest >> 2;

  // ---- stage transposed x tile: rows 0..259 (t = t0-64+row), cols f0-16+[0,64) ----
  for (int i = tid; i < ROWS * 8; i += 256) {
    int row = i >> 3, fc = i & 7;
    int t = t0 - 64 + row;
    int f = f0 - 16 + fc * 8;
    uint4 v = make_uint4(0u, 0u, 0u, 0u);
    if (t >= 0 && t < Tj && f >= 0 && f < 128)
      v = *(const uint4*)(xT + ((size_t)b * Tj + t) * 128 + f);
    *(uint4*)&xt[row * PITCH + fc * 8] = v;
  }
  __syncthreads();

  const int wave = tid >> 6, lane = tid & 63;
  const int n  = lane & 31;                // B col = t position
  const int h  = lane >> 5;                // k-half = dt sub-index; wavelet half
  const int ch = lane & 15;                // A row low = channel
  const int ps = (lane >> 4) & 1;          // A row high = +4 plane shift
  const float invw = 1.0f / (float)(1 << lw);

  for (int rho = 0; rho < 4; ++rho) {
    const ushort* wb =
        wq + ((((size_t)(oct * 4 + rho) * 2 + ps) * 16 + ch) * DTP + h) * D2;
    const int rb0 = (32 * wave + n + h) * PITCH;

    f32x16 acc[4];
#pragma unroll
    for (int k = 0; k < 4; ++k)
#pragma unroll
      for (int e = 0; e < 16; ++e) acc[k][e] = 0.f;

    short8 F0[5], F1[5], F2[5];

    auto load5 = [](short8 (&F)[5], const ushort* ptr) {
#pragma unroll
      for (int u = 0; u < 5; ++u) F[u] = load_a16(ptr + 8 * u);
    };

    // young half of c (s=0..3) interleaved with old half of c-1 (s=4..7);
    // rby = row base of c (old reads rby - 2*PITCH).
    auto half = [&](short8 (&Fy)[5], short8 (&Fo)[5], int rby) {
      __builtin_amdgcn_s_setprio(1);
#pragma unroll
      for (int ss = 0; ss < 4; ++ss) {
        short8 bvy = *(const short8*)&xt[rby + ss * 8];
#pragma unroll
        for (int kd = 3; kd >= 0; --kd)
          if (kd <= ss)
            acc[kd] = __builtin_amdgcn_mfma_f32_32x32x16_bf16(Fy[ss - kd], bvy, acc[kd], 0, 0, 0);
        short8 bvo = *(const short8*)&xt[rby - 2 * PITCH + (ss + 4) * 8];
#pragma unroll
        for (int kd = 3; kd >= 0; --kd)
          if (kd >= ss)
            acc[kd] = __builtin_amdgcn_mfma_f32_32x32x16_bf16(Fo[ss + 4 - kd], bvo, acc[kd], 0, 0, 0);
      }
      __builtin_amdgcn_s_setprio(0);
    };

    auto halfY = [&](short8 (&Fy)[5], int rby) {     // young-only (c=0)
      __builtin_amdgcn_s_setprio(1);
#pragma unroll
      for (int ss = 0; ss < 4; ++ss) {
        short8 bvy = *(const short8*)&xt[rby + ss * 8];
#pragma unroll
        for (int kd = 3; kd >= 0; --kd)
          if (kd <= ss)
            acc[kd] = __builtin_amdgcn_mfma_f32_32x32x16_bf16(Fy[ss - kd], bvy, acc[kd], 0, 0, 0);
      }
      __builtin_amdgcn_s_setprio(0);
    };

    auto halfO = [&](short8 (&Fo)[5], int rbo) {     // old-only (c=64)
      __builtin_amdgcn_s_setprio(1);
#pragma unroll
      for (int ss = 0; ss < 4; ++ss) {
        short8 bvo = *(const short8*)&xt[rbo + (ss + 4) * 8];
#pragma unroll
        for (int kd = 3; kd >= 0; --kd)
          if (kd >= ss)
            acc[kd] = __builtin_amdgcn_mfma_f32_32x32x16_bf16(Fo[ss + 4 - kd], bvo, acc[kd], 0, 0, 0);
      }
      __builtin_amdgcn_s_setprio(0);
    };

    // 65 c's; schedule = halfY(c0), 21x3 interleaved halves, half(c64,c63), halfO(c64)
    load5(F0, wb);                     // c0
    load5(F1, wb + 2 * D2);            // c1
    halfY(F0, rb0);
    const ushort* wp = wb;
    int rb = rb0;
#pragma unroll 1
    for (int cc = 0; cc < 21; ++cc) {
      load5(F2, wp + 4 * D2);  half(F1, F0, rb + 2 * PITCH);   // young c1', old c0'
      load5(F0, wp + 6 * D2);  half(F2, F1, rb + 4 * PITCH);
      load5(F1, wp + 8 * D2);  half(F0, F2, rb + 6 * PITCH);
      wp += 6 * D2; rb += 6 * PITCH;
    }
    half(F1, F0, rb + 2 * PITCH);      // young c64, old c63
    halfO(F1, rb + 2 * PITCH);         // old c64 (rows rb_c64 + (s)*..)

    // ---- epilogue: per-lane modulus + pool butterfly + store ----
#pragma unroll
    for (int k = 0; k < 4; ++k) {
#pragma unroll
      for (int p2 = 0; p2 < 2; ++p2) {
        const int fo = f0 + rho + 4 * p2 + 8 * k;
#pragma unroll
        for (int bi = 0; bi < 4; ++bi) {
          float re = acc[k][8 * p2 + bi];
          float im = acc[k][8 * p2 + 4 + bi];
          float m = sqrtf(re * re + im * im);
          m += __shfl_xor(m, 1);
          if (lw >= 2) m += __shfl_xor(m, 2);
          if (lw >= 3) m += __shfl_xor(m, 4);
          if (lw >= 4) m += __shfl_xor(m, 8);
          if ((n & ((1 << lw) - 1)) == 0) {
            const int wvl = 4 * h + bi;
            const int tcol = (t0 + 32 * wave + n) >> lw;
            out[(((size_t)b * 32 + oct * 8 + wvl) * 128 + fo) * 1024 + tcol] =
                m * invw;
          }
        }
      }
    }
  }
}

// ---------------------------------------------------------------------------
extern "C" void kernel_launch(void* const* d_in, const int* in_sizes, int n_in,
                              void* d_out, int out_size, void* d_ws, size_t ws_size,
                              hipStream_t stream) {
  const float* x  = (const float*)d_in[0];
  const float* wr = (const float*)d_in[1];
  const float* wi = (const float*)d_in[2];
  float* out = (float*)d_out;

  ushort* xT0 = (ushort*)d_ws;                       // 4*16384*128
  ushort* xT1 = xT0 + (size_t)4 * 16384 * 128;       // 4*8192*128
  ushort* xT2 = xT1 + (size_t)4 * 8192 * 128;        // 4*4096*128
  ushort* xT3 = xT2 + (size_t)4 * 4096 * 128;        // 4*2048*128
  ushort* wq  = xT3 + (size_t)4 * 2048 * 128;        // 2703360

  prep_w<<<2703360 / 256, 256, 0, stream>>>(wr, wi, wq);
  prep_x<<<dim3(T_FULL / 64, B_), 256, 0, stream>>>(x, xT0, xT1, xT2, xT3);

  conv_mfma<<<3840, 256, 0, stream>>>(xT0, xT1, xT2, xT3, wq, out);
}

// Round 15
// 1591.091 us; speedup vs baseline: 1.7097x; 1.2358x over previous
//
#include <hip/hip_runtime.h>
#include <math.h>

#define B_      4
#define F_BINS  128
#define T_FULL  16384
#define KF      33
#define KT      129

// conv tile geometry: f-tile 32 planes x TT 128 t per block
#define TT      128
#define ROWS    260                // TT + 132 halo
#define PITCH   72                 // ushort pitch for 64 f cols (16B-aligned rows)
#define DTP     136                // padded dt rows in wq (129 + pad for prefetch)
#define D2      48                 // padded d2 window

typedef __attribute__((ext_vector_type(8))) short short8;
typedef __attribute__((ext_vector_type(4))) float f32x4;
typedef uint uint4a16 __attribute__((ext_vector_type(4), aligned(16)));

union ABFrag { uint4a16 u; short8 v; };

__device__ __forceinline__ ushort f2bf(float v) {
  unsigned u = __float_as_uint(v);
  unsigned r = (u + 0x7FFFu + ((u >> 16) & 1u)) >> 16;
  return (ushort)r;
}

__device__ __forceinline__ short8 load_a16(const ushort* p) {
  ABFrag f; f.u = *(const uint4a16*)p; return f.v;
}

__device__ __forceinline__ short8 mkG(short8 a, short8 b) {
  return __builtin_shufflevector(a, b, 4, 5, 6, 7, 8, 9, 10, 11);
}

// ---------------------------------------------------------------------------
// prep_w: gamma-shifted, zero-padded bf16 weights
//   wq[oct 4][gam 4][ch 16][dt 136][d2 48] = wav[ch][df = d2 - 4 - gam][dt]
//   zero outside df in [0,33), dt in [0,129). Planes fo = f0+gam+4k share
//   this block via register-window shifts (F/G fragments).
// ---------------------------------------------------------------------------
__global__ __launch_bounds__(256) void prep_w(
    const float* __restrict__ wr, const float* __restrict__ wi,
    ushort* __restrict__ wq) {
  int idx = blockIdx.x * 256 + threadIdx.x;      // 4*4*16*136*48 = 1671168
  int d2  = idx % D2;
  int dt  = (idx / D2) % DTP;
  int ch  = (idx / (D2 * DTP)) % 16;
  int gam = (idx / (D2 * DTP * 16)) % 4;
  int oct = idx / (D2 * DTP * 16 * 4);
  int df  = d2 - 4 - gam;
  float v = 0.f;
  if (df >= 0 && df < KF && dt < KT) {
    const float* src = (ch < 8) ? wr : wi;
    v = src[(((size_t)oct * 8 + (ch & 7)) * KF + df) * KT + dt];
  }
  wq[idx] = f2bf(v);
}

// ---------------------------------------------------------------------------
// prep_x: bf16 transposed pyramid  xTj[b][T_j][128f]  for j=0..3
// ---------------------------------------------------------------------------
__global__ __launch_bounds__(256) void prep_x(
    const float* __restrict__ x,
    ushort* __restrict__ xT0, ushort* __restrict__ xT1,
    ushort* __restrict__ xT2, ushort* __restrict__ xT3) {
  __shared__ float lt[128 * 65];
  const int b  = blockIdx.y;
  const int t0 = blockIdx.x * 64;
  const int tid = threadIdx.x;
  const int wv = tid >> 6, lane = tid & 63;
#pragma unroll
  for (int rep = 0; rep < 32; ++rep) {
    int f = rep * 4 + wv;
    lt[f * 65 + lane] = x[((size_t)b * 128 + f) * T_FULL + t0 + lane];
  }
  __syncthreads();
  ushort* dst[4] = {xT0, xT1, xT2, xT3};
  const int Ts[4] = {16384, 8192, 4096, 2048};
  for (int lvl = 0; lvl < 4; ++lvl) {
    int nt = 64 >> lvl, w = 1 << lvl;
    float inv = 1.f / (float)w;
    int tasks = nt * 16;
    for (int i = tid; i < tasks; i += 256) {
      int tl = i >> 4, fc = i & 15;
      __align__(16) ushort vs[8];
#pragma unroll
      for (int e = 0; e < 8; ++e) {
        float a = 0.f;
        for (int m = 0; m < w; ++m) a += lt[(fc * 8 + e) * 65 + tl * w + m];
        vs[e] = f2bf(a * inv);
      }
      ushort* pdst = dst[lvl] + ((size_t)b * Ts[lvl] + (t0 >> lvl) + tl) * 128 + fc * 8;
      *(uint4*)pdst = *(const uint4*)vs;
    }
  }
}

// ---------------------------------------------------------------------------
// conv_mfma: ALL octaves fused in one grid of 3840 equal-work blocks.
// XCD-aware bijective swizzle (3840 = 8 x 480): logical = (bx&7)*480 + bx>>3,
// so consecutive logical tiles (same octave, shared wq slice + x halos) land
// on the same XCD's L2.
//   logical [0,2048) oct0, [2048,3072) oct1, [3072,3584) oct2, [3584,3840) oct3
// Block = 256 thr = 4 waves; tile = 32 f_out x 128 t.
// MFMA 16x16x32_bf16: M=ch16 (A=weights), N=pos16 (B=x), K=(4 dt x 8 d2).
// Per gamma-iter computes 8 output-f planes fo = f0 + gamma + 4k (k=0..7):
//   odd  k: A = F[s - (k-1)/2] ; even k: A = G[s - k/2]
// with per-plane active s in [s_lo(k), s_lo(k)+4], s_lo = {0,0,1,1,2,2,3,3}.
// Epilogue deduped: lo lanes (g<2) finish r=0,1; hi lanes finish r=2,3.
// ---------------------------------------------------------------------------
__global__ __launch_bounds__(256, 3) void conv_mfma(
    const ushort* __restrict__ xT0, const ushort* __restrict__ xT1,
    const ushort* __restrict__ xT2, const ushort* __restrict__ xT3,
    const ushort* __restrict__ wq, float* __restrict__ out) {
  __shared__ ushort xt[ROWS * PITCH];
  const int tid = threadIdx.x;
  const int bxh = blockIdx.x;
  const int bx = (bxh & 7) * 480 + (bxh >> 3);   // XCD-aware bijective swizzle

  int oct, local;
  if (bx < 2048)      { oct = 0; local = bx; }
  else if (bx < 3072) { oct = 1; local = bx - 2048; }
  else if (bx < 3584) { oct = 2; local = bx - 3072; }
  else                { oct = 3; local = bx - 3584; }
  const ushort* xT = (oct == 0) ? xT0 : (oct == 1) ? xT1 : (oct == 2) ? xT2 : xT3;
  const int Tj = T_FULL >> oct;
  const int lw = 4 - oct;                     // pool window = 1<<lw
  const int nxs = 7 - oct;                    // nx = 128>>oct
  const int tx = local & ((1 << nxs) - 1);
  const int rest = local >> nxs;
  const int t0 = tx * TT;
  const int f0 = (rest & 3) * 32;
  const int b  = rest >> 2;

  // ---- stage transposed x tile: rows 0..259 (t = t0-64+row), cols f0-16+[0,64) ----
  for (int i = tid; i < ROWS * 8; i += 256) {
    int row = i >> 3, fc = i & 7;
    int t = t0 - 64 + row;
    int f = f0 - 16 + fc * 8;             // chunk fully in or fully out of range
    uint4 v = make_uint4(0u, 0u, 0u, 0u);
    if (t >= 0 && t < Tj && f >= 0 && f < 128)
      v = *(const uint4*)(xT + ((size_t)b * Tj + t) * 128 + f);
    *(uint4*)&xt[row * PITCH + fc * 8] = v;
  }
  __syncthreads();

  const int wave = tid >> 6, lane = tid & 63;
  const int p = lane & 15;                 // A-row = channel sel, B-col = position
  const int g = lane >> 4;                 // k-group (dt sub-index)
  const int hi = (lane >= 32);
  const float invw = 1.0f / (float)(1 << lw);

  for (int gamma = 0; gamma < 4; ++gamma) {
    const ushort* wbase = wq + ((((size_t)oct * 4 + gamma) * 16 + p) * DTP + g) * D2;
    const ushort* wp = wbase + 4 * D2;     // in-body loads fetch c+1
    int rb = (p + g) * PITCH + wave * (32 * PITCH);

    f32x4 acc[8][2];
#pragma unroll
    for (int k = 0; k < 8; ++k)
#pragma unroll
      for (int r = 0; r < 2; ++r) { f32x4 z = {0.f, 0.f, 0.f, 0.f}; acc[k][r] = z; }

    short8 F[6], G[5];
#pragma unroll
    for (int u = 0; u < 6; ++u) F[u] = load_a16(wbase + 8 * u);
    G[0] = mkG(F[0], F[1]);
    G[1] = mkG(F[1], F[2]);

#pragma unroll 1
    for (int c = 0; c < 33; ++c) {
      __builtin_amdgcn_s_setprio(1);
      const int SLO[8] = {0, 0, 1, 1, 2, 2, 3, 3};
#pragma unroll
      for (int s = 0; s < 8; ++s) {
        if (s == 0) G[2] = mkG(F[2], F[3]);
        if (s == 1) G[3] = mkG(F[3], F[4]);
        if (s == 2) G[4] = mkG(F[4], F[5]);
        short8 bv0 = *(const short8*)&xt[rb + s * 8];
        short8 bv1 = *(const short8*)&xt[rb + 16 * PITCH + s * 8];
#pragma unroll
        for (int k = 0; k < 8; ++k) {
          if (s >= SLO[k] && s <= SLO[k] + 4) {
            const int idx = s - SLO[k];
            short8 a = (k & 1) ? F[idx] : G[idx];
            acc[k][0] = __builtin_amdgcn_mfma_f32_16x16x32_bf16(a, bv0, acc[k][0], 0, 0, 0);
            acc[k][1] = __builtin_amdgcn_mfma_f32_16x16x32_bf16(a, bv1, acc[k][1], 0, 0, 0);
          }
        }
        // in-place prefetch of next-c fragments (after last use this c)
        if (s >= 3) F[s - 3] = load_a16(wp + 8 * (s - 3));
        if (s == 6) G[0] = mkG(F[0], F[1]);   // next-c G
        if (s == 7) G[1] = mkG(F[1], F[2]);   // next-c G
      }
      F[5] = load_a16(wp + 40);
      __builtin_amdgcn_s_setprio(0);
      wp += 4 * D2;                // dt += 4
      rb += 4 * PITCH;             // row += 4
    }

    // ---- epilogue: modulus + avg-pool, deduped across lane halves ----
    // lo lanes (g=0,1) finish r=0,1 -> ch 4g+{0,1};
    // hi lanes (g=2,3) finish r=2,3 -> ch 4(g-2)+{2,3}.
#pragma unroll
    for (int k = 0; k < 8; ++k) {
      const int fo = f0 + gamma + 4 * k;
#pragma unroll
      for (int fr = 0; fr < 2; ++fr) {
        const int tbase = t0 + 32 * wave + 16 * fr;
        float sq[4];
#pragma unroll
        for (int r = 0; r < 4; ++r) {
          float a = acc[k][fr][r];
          float o = __shfl_xor(a, 32);
          sq[r] = a * a + o * o;
        }
        float m0 = sqrtf(hi ? sq[2] : sq[0]);
        float m1 = sqrtf(hi ? sq[3] : sq[1]);
        if (lw == 4) { m0 += __shfl_xor(m0, 8); m1 += __shfl_xor(m1, 8); }
        if (lw >= 3) { m0 += __shfl_xor(m0, 4); m1 += __shfl_xor(m1, 4); }
        if (lw >= 2) { m0 += __shfl_xor(m0, 2); m1 += __shfl_xor(m1, 2); }
        m0 += __shfl_xor(m0, 1);  m1 += __shfl_xor(m1, 1);
        if ((p & ((1 << lw) - 1)) == 0) {
          const int ch0 = 4 * (g & 1) + (hi ? 2 : 0);
          const int tcol = (tbase + p) >> lw;
          size_t o0 = (((size_t)b * 32 + oct * 8 + ch0) * 128 + fo) * 1024 + tcol;
          out[o0] = m0 * invw;
          out[o0 + (size_t)128 * 1024] = m1 * invw;   // ch0+1
        }
      }
    }
  }
}

// ---------------------------------------------------------------------------
extern "C" void kernel_launch(void* const* d_in, const int* in_sizes, int n_in,
                              void* d_out, int out_size, void* d_ws, size_t ws_size,
                              hipStream_t stream) {
  const float* x  = (const float*)d_in[0];
  const float* wr = (const float*)d_in[1];
  const float* wi = (const float*)d_in[2];
  float* out = (float*)d_out;

  ushort* xT0 = (ushort*)d_ws;                       // 4*16384*128
  ushort* xT1 = xT0 + (size_t)4 * 16384 * 128;       // 4*8192*128
  ushort* xT2 = xT1 + (size_t)4 * 8192 * 128;        // 4*4096*128
  ushort* xT3 = xT2 + (size_t)4 * 4096 * 128;        // 4*2048*128
  ushort* wq  = xT3 + (size_t)4 * 2048 * 128;        // 1671168

  prep_w<<<1671168 / 256, 256, 0, stream>>>(wr, wi, wq);
  prep_x<<<dim3(T_FULL / 64, B_), 256, 0, stream>>>(x, xT0, xT1, xT2, xT3);

  conv_mfma<<<3840, 256, 0, stream>>>(xT0, xT1, xT2, xT3, wq, out);
}